// Round 8
// baseline (123.037 us; speedup 1.0000x reference)
//
#include <hip/hip_runtime.h>
#include <hip/hip_bf16.h>

#define N_SPK 2048
#define M_UTT 10
#define D_DIM 256
#define NM (N_SPK * M_UTT)   // 20480

typedef __attribute__((ext_vector_type(8))) short bf16x8_t;
typedef __attribute__((ext_vector_type(16))) float f32x16_t;

__device__ __forceinline__ short f2bf(float x) {
  __hip_bfloat16 h = __float2bfloat16(x);
  return *reinterpret_cast<short*>(&h);
}

// ---------------- K1: fused prep ----------------
// One block per speaker n (2048 blocks x 256 threads, d = tid):
//  - centroid v = sum_m(e) / max(||sum||, 1e-11)  (== mean/max(||mean||,1e-12))
//  - Bf: centroid in 32x32x16 MFMA A-frag order (verified layout)
//  - embn: normalized rows in the SAME 32x32x16 frag order (B operand)
//  - zero rowsum rows, possum slots, out[0]
// (dvals path removed: positive-pair cos is extracted from the GEMM diagonal)
__global__ __launch_bounds__(256) void k_prep(const float* __restrict__ emb,
                                              __hip_bfloat16* __restrict__ Bf,
                                              __hip_bfloat16* __restrict__ embn,
                                              float* __restrict__ rowsum,
                                              float* __restrict__ possum,
                                              float* __restrict__ out) {
  const int n = blockIdx.x, d = threadIdx.x;
  const int wid = d >> 6, lane = d & 63;
  const float* p = emb + (size_t)n * (M_UTT * D_DIM) + d;

  float e[M_UTT];
  float s = 0.f;
#pragma unroll
  for (int m = 0; m < M_UTT; ++m) { e[m] = p[m * D_DIM]; s += e[m]; }

  // centroid norm (block reduce of s^2)
  float ss = s * s;
#pragma unroll
  for (int o = 32; o >= 1; o >>= 1) ss += __shfl_xor(ss, o, 64);
  __shared__ float redc[4];
  if (lane == 0) redc[wid] = ss;
  __syncthreads();
  float tot = redc[0] + redc[1] + redc[2] + redc[3];
  float inv = 1.0f / fmaxf(sqrtf(tot), 1e-11f);
  float v = s * inv;

  // Bf fragment layout (verified rounds 2-7)
  int idx = (((n >> 5) * 16 + (d >> 4)) * 64 + ((d >> 3) & 1) * 32 + (n & 31)) * 8 + (d & 7);
  Bf[idx] = __float2bfloat16(v);

  // per-utterance ||e||^2 (block reduces)
  __shared__ float redm[M_UTT][4];
#pragma unroll
  for (int m = 0; m < M_UTT; ++m) {
    float a = e[m] * e[m];
#pragma unroll
    for (int o = 32; o >= 1; o >>= 1) a += __shfl_xor(a, o, 64);
    if (lane == 0) redm[m][wid] = a;
  }
  __syncthreads();
  __shared__ float rnb[M_UTT];
  if (d < M_UTT) {
    float ssm = redm[d][0] + redm[d][1] + redm[d][2] + redm[d][3];
    rnb[d] = 1.0f / fmaxf(sqrtf(ssm), 1e-12f);
    rowsum[n * M_UTT + d] = 0.f;
  }
  if (n == 0) {
    if (d < 64) possum[d] = 0.f;
    if (d == 0) out[0] = 0.f;
  }
  __syncthreads();

  short* eo = (short*)embn;
#pragma unroll
  for (int m = 0; m < M_UTT; ++m) {
    int row = n * M_UTT + m;
    int u = (((row >> 5) * 16 + (d >> 4)) * 64 + ((d >> 3) & 1) * 32 + (row & 31));
    eo[u * 8 + (d & 7)] = f2bf(e[m] * rnb[m]);
  }
}

// ---------------- K2: fused GEMM + exp row-sums + diagonal pos ----------------
// Block = 4 waves = 256 emb rows x 128 cent cols. Bijective XCD remap (r7).
// NEW (a): split-wait staging — Bs stage drains alone before the barrier;
//          breg's 32 loads issue after and trickle in under the K-loop.
// NEW (b): positive-pair cos extracted from the MFMA output diagonal
//          (C/D layout: cent-row = (r&3)+8*(r>>2)+4*lh, emb-col = l31),
//          wave-reduced, one atomicAdd into possum[lid&63].
__global__ __launch_bounds__(256, 2) void k_gemm(const __hip_bfloat16* __restrict__ embn,
                                                 const __hip_bfloat16* __restrict__ Bf,
                                                 float* __restrict__ rowsum,
                                                 float* __restrict__ possum,
                                                 const float* __restrict__ wp) {
  __shared__ short Bs[128 * 256];  // 64 KB: 4 col-groups x 16 ks x 64 units x 8
  const float aw = fabsf(wp[0]);
  const int tid = threadIdx.x;
  const int lane = tid & 63, w = tid >> 6;
  const int l31 = lane & 31, lh = lane >> 5;

  const int lid = blockIdx.x + 16 * blockIdx.y;  // 0..1279
  const int xcd = lid & 7;
  const int slot = lid >> 3;                     // 0..159
  const int colsplit = slot & 15;                // inner: col-splits back-to-back
  const int rowg = xcd + 8 * (slot >> 4);        // 0..79, rowg == xcd (mod 8)

  const int row0 = rowg * 256 + w * 64;          // this wave's 64 emb rows
  const int Rb = rowg * 8 + w * 2;               // 32-row block index

  // ---- stage this block's 128 centroid cols into LDS (linear copy) ----
  {
    const short* src = (const short*)Bf + (size_t)colsplit * 32768 + w * 512 + lane * 8;
#pragma unroll
    for (int it = 0; it < 16; ++it) {
      __builtin_amdgcn_global_load_lds(
          (const __attribute__((address_space(1))) void*)(src + it * 2048),
          (__attribute__((address_space(3))) void*)&Bs[it * 2048 + w * 512],
          16, 0, 0);
    }
  }
  asm volatile("s_waitcnt vmcnt(0)" ::: "memory");
  __syncthreads();

  // ---- breg: issued AFTER the barrier; compiler inserts counted waits so
  //      the loads overlap the first K-iterations ----
  const bf16x8_t* fp = (const bf16x8_t*)embn;
  bf16x8_t breg[2][16];
#pragma unroll
  for (int rg = 0; rg < 2; ++rg)
#pragma unroll
    for (int ks = 0; ks < 16; ++ks)
      breg[rg][ks] = fp[(size_t)((Rb + rg) * 16 + ks) * 64 + lane];

  // speaker (positive col) for each of this lane's 2 rows
  const int spk0 = ((Rb + 0) * 32 + l31) / M_UTT;
  const int spk1 = ((Rb + 1) * 32 + l31) / M_UTT;
  const int cb128 = colsplit * 128 + 4 * lh;  // + (2c+ci)*32 + (r&3)+8*(r>>2)

  float rowacc[2] = {0.f, 0.f};
  float posacc = 0.f;

#pragma unroll
  for (int c = 0; c < 2; ++c) {
    f32x16_t acc[2][2];
#pragma unroll
    for (int rg = 0; rg < 2; ++rg)
#pragma unroll
      for (int ci = 0; ci < 2; ++ci)
#pragma unroll
        for (int r = 0; r < 16; ++r) acc[rg][ci][r] = 0.f;

#pragma unroll
    for (int ks = 0; ks < 16; ++ks) {
      bf16x8_t c0 = *(const bf16x8_t*)&Bs[((2 * c) * 16 + ks) * 512 + lane * 8];
      bf16x8_t c1 = *(const bf16x8_t*)&Bs[((2 * c + 1) * 16 + ks) * 512 + lane * 8];
      acc[0][0] = __builtin_amdgcn_mfma_f32_32x32x16_bf16(c0, breg[0][ks], acc[0][0], 0, 0, 0);
      acc[0][1] = __builtin_amdgcn_mfma_f32_32x32x16_bf16(c1, breg[0][ks], acc[0][1], 0, 0, 0);
      acc[1][0] = __builtin_amdgcn_mfma_f32_32x32x16_bf16(c0, breg[1][ks], acc[1][0], 0, 0, 0);
      acc[1][1] = __builtin_amdgcn_mfma_f32_32x32x16_bf16(c1, breg[1][ks], acc[1][1], 0, 0, 0);
    }

    // exp-epilogue + diagonal extraction (compare folds to a constant per r)
#pragma unroll
    for (int rg = 0; rg < 2; ++rg) {
      const int spk = rg ? spk1 : spk0;
      float s = 0.f;
#pragma unroll
      for (int ci = 0; ci < 2; ++ci) {
        const int tbase = cb128 + (2 * c + ci) * 32;
#pragma unroll
        for (int r = 0; r < 16; ++r) {
          float a = acc[rg][ci][r];
          s += __expf(fmaf(aw, a, -aw));
          if (tbase + ((r & 3) + 8 * (r >> 2)) == spk) posacc += a;
        }
      }
      rowacc[rg] += s;
    }
  }

  // combine lh halves, one atomic per row
#pragma unroll
  for (int rg = 0; rg < 2; ++rg) {
    float s = rowacc[rg] + __shfl_xor(rowacc[rg], 32, 64);
    if (lane < 32) atomicAdd(&rowsum[row0 + rg * 32 + lane], s);
  }

  // wave-reduce positive-pair sum, one atomic per wave into 64 slots
#pragma unroll
  for (int o = 32; o >= 1; o >>= 1) posacc += __shfl_xor(posacc, o, 64);
  if (lane == 0) atomicAdd(&possum[lid & 63], posacc);
}

// ---------------- K3: final reduction -> scalar loss ----------------
// out = aw + [ sum_r log(rowsum_r) - aw * sum(possum) ] / NM   (b cancels)
__global__ __launch_bounds__(256) void k_final(const float* __restrict__ rowsum,
                                               const float* __restrict__ possum,
                                               const float* __restrict__ wp,
                                               float* __restrict__ out) {
  const float aw = fabsf(wp[0]);
  int base = blockIdx.x * 512 + threadIdx.x;
  float c = logf(rowsum[base]) + logf(rowsum[base + 256]);
  if (blockIdx.x == 0 && threadIdx.x < 64) c -= aw * possum[threadIdx.x];
#pragma unroll
  for (int o = 32; o >= 1; o >>= 1) c += __shfl_xor(c, o, 64);
  __shared__ float rs[4];
  int wid = threadIdx.x >> 6, lane = threadIdx.x & 63;
  if (lane == 0) rs[wid] = c;
  __syncthreads();
  if (threadIdx.x == 0) {
    float blocksum = rs[0] + rs[1] + rs[2] + rs[3];
    atomicAdd(out, blocksum * (1.0f / (float)NM) + (blockIdx.x == 0 ? aw : 0.f));
  }
}

extern "C" void kernel_launch(void* const* d_in, const int* in_sizes, int n_in,
                              void* d_out, int out_size, void* d_ws, size_t ws_size,
                              hipStream_t stream) {
  const float* emb = (const float*)d_in[0];
  const float* wp  = (const float*)d_in[1];
  float* out = (float*)d_out;

  char* ws = (char*)d_ws;
  float* rowsum = (float*)(ws);                             // 80 KB @ 0
  float* possum = (float*)(ws + (96 << 10));                // 256 B @ 96K
  __hip_bfloat16* Bf   = (__hip_bfloat16*)(ws + (1 << 20)); // 1 MB @ 1M (frag order)
  __hip_bfloat16* embn = (__hip_bfloat16*)(ws + (2 << 20)); // 10 MB @ 2M (frag order)

  k_prep<<<N_SPK, 256, 0, stream>>>(emb, Bf, embn, rowsum, possum, out);
  k_gemm<<<dim3(16, NM / 256), 256, 0, stream>>>(embn, Bf, rowsum, possum, wp);
  k_final<<<NM / 512, 256, 0, stream>>>(rowsum, possum, wp, out);
}